// Round 4
// baseline (339.867 us; speedup 1.0000x reference)
//
#include <hip/hip_runtime.h>

// InfoNCE loss:
//   loss = (1/B) * sum_i [ log(sum_j exp(Q_i . D_j / T)) - Q_i . D_{i*dp} / T ]
//
// R8 = m201-style 8-phase 256x256 MX-fp8 GEMM (T3+T4+T5), replacing the
// m97-type 2-barrier 128x128 loop that R7 showed is AT its structural
// ceiling (1521 TF = 93% of the documented fp8-MX m97-structure point;
// FETCH halved by XCD swizzle with zero time change => not memory-bound,
// barrier-drain-bound).
//
//  - 256x256 tile, 8 waves (2M x 4N), per-wave C = 128x64 = 32 frags
//    (16x16x128 MFMA, acc = 32 x f32x4 = 128 VGPR).
//  - LDS 128KB: 2 ring slots x (A 32KB + B 32KB), full-K (BK=128) tiles.
//  - Per K-tile: 4 phases, each = one C-quadrant (Mh,Nh):
//      12 ds_read_b128 (4 A-frags + 2 B-frags) from buf[cur]
//      2 global_load_lds chunks of tile kb+1 into buf[cur^1]
//      s_barrier ; lgkmcnt(0) ; setprio(1) ; 8 MFMA ; setprio(0)
//      [phase 3 only: vmcnt(0) -- every prefetch load aged >=1 MFMA
//       cluster (~550cy) > L2 latency, so this drain is covered]
//      s_barrier
//  - Staging: 64 x 1KB chunks per tile; wave w issues chunks w*8+2p..+1 in
//    phase p (waves 0-3 stage A, 4-7 stage B). Lane-linear on both sides.
//  - XCD swizzle (verified in R7: FETCH halved): 512 blocks = 8 XCDs x
//    (8bx x 8by) sub-tiles; per-XCD slab = 2MB A + 2MB B = one 4MB L2.
//
// Tiled global layout (per matrix, unchanged): for 128-row block R, 128-wide
// k-block k0b: 16KB image = 16 chunks x 1KB. Chunk c = rg*2 + kh (rg=0..7
// 16-row group, kh=0..1 64-col half); slot l (16B) holds
//   X[R*128 + rg*16 + (l&15)][k0b*128 + kh*64 + (l>>4)*16 .. +16]   (fp8)
//
// ws layout (~12.1 MB):
//   [0)       Q8  B*K fp8     (4 MB)
//   [B*K)     D8  N*K fp8     (8 MB)
//   [+N*K)    rowsum B f32    (16 KB)  zeroed by cvt kernel
//   [+B*4)    pos    B f32    (16 KB)  written by gemm epilogue

#define TEMP_INV 50.0f
#define PRESCALE 16.0f
#define SCALE_BYTE 123   // e8m0: 2^(123-127) = 2^-4 per operand

typedef int   i32x4 __attribute__((ext_vector_type(4)));
typedef int   i32x8 __attribute__((ext_vector_type(8)));
typedef float f32x4 __attribute__((ext_vector_type(4)));

// ---------------- fp32 -> fp8 e4m3 (x16), pre-tiled; zero rowsum ----------
__global__ void cvt_kernel(const float* __restrict__ Q, const float* __restrict__ Dm,
                           unsigned int* __restrict__ Q8, unsigned int* __restrict__ D8,
                           float* __restrict__ rowsum, int qSlots, int B, int K) {
    const int gid = blockIdx.x * blockDim.x + threadIdx.x;
    if (gid < B) rowsum[gid] = 0.0f;
    const float* src;
    unsigned int* dst;
    int s;
    if (gid < qSlots) { src = Q;  dst = Q8; s = gid; }
    else              { src = Dm; dst = D8; s = gid - qSlots; }
    // Slot permutation within the 64-slot chunk (R7, kept): lane l handles
    // slot ((l&3)<<4)|(l>>2) -> reads coalesce to 256B runs.
    {
        const int l0 = s & 63;
        s = (s & ~63) | (((l0 & 3) << 4) | (l0 >> 2));
    }
    const int l   = s & 63;
    const int c   = (s >> 6) & 15;
    const int k0b = (s >> 10) & 7;
    const int R   = s >> 13;
    const int row = R * 128 + (c >> 1) * 16 + (l & 15);
    const int k   = k0b * 128 + (c & 1) * 64 + (l >> 4) * 16;
    const float* p = src + (size_t)row * K + k;
    unsigned int w[4];
#pragma unroll
    for (int d = 0; d < 4; ++d) {
        float4 v = *(const float4*)(p + d * 4);
        int t = __builtin_amdgcn_cvt_pk_fp8_f32(v.x * PRESCALE, v.y * PRESCALE, 0, false);
        t = __builtin_amdgcn_cvt_pk_fp8_f32(v.z * PRESCALE, v.w * PRESCALE, t, true);
        w[d] = (unsigned int)t;
    }
    *(uint4*)(dst + (size_t)s * 4) = make_uint4(w[0], w[1], w[2], w[3]);
}

// ---------------- fused MX-fp8 GEMM + row sum-exp + pos extraction --------
// grid: 1D 512 blocks (XCD-swizzled -> bx in [0,16), by in [0,32)),
// 512 threads = 8 waves (2x4), BK=128, 4-phase schedule, 128KB LDS ring.
__global__ __launch_bounds__(512, 2) void gemm_expsum_kernel(
        const unsigned int* __restrict__ Q8, const unsigned int* __restrict__ D8,
        const int* __restrict__ dper,
        float* __restrict__ rowsum, float* __restrict__ pos, int K) {
    __shared__ unsigned int BUF[32768];   // 128KB: 2 x (A 8192 dw + B 8192 dw)

    const int tid   = threadIdx.x;
    const int wave  = tid >> 6;
    const int lane  = tid & 63;
    const int wr    = wave >> 2;         // 0..1 -> 128-row half
    const int wc    = wave & 3;          // 0..3 -> 64-col strip
    const int lquad = lane >> 4;
    const int lm    = lane & 15;
    const int lh2   = lquad >> 1;        // kh for fragment reads

    // XCD-aware bijective swizzle: 512 = 8 XCDs x (8bx x 8by) sub-tiles.
    const int f   = blockIdx.x;
    const int xcd = f & 7;
    const int sub = f >> 3;              // 0..63
    const int bx  = (xcd & 1) * 8 + (sub & 7);    // 0..15
    const int by  = (xcd >> 1) * 8 + (sub >> 3);  // 0..31

    const int KB = K >> 7;               // 8 K-tiles of 128

    // ---- staging setup: wave w owns chunks flat = w*8 + 2p + q ----
    // flat<32 -> A chunk ca=flat (rb=ca>>4 image, c=ca&15 within image);
    // flat>=32 -> B chunk cb=flat-32. waves 0-3 <=> A, 4-7 <=> B.
    const unsigned int* sbase = (wave < 4) ? Q8 : D8;
    const int bb = (wave < 4) ? bx : by;
    unsigned int sidx[8];                // dword index from sbase (+kb*4096)
    unsigned int dofs[8];                // dword offset in ring slot
#pragma unroll
    for (int q = 0; q < 8; ++q) {
        const int fl = (wave & 3) * 8 + q;        // 0..31 within A or B set
        const int rb = fl >> 4;                   // which 128-row image
        const int c  = fl & 15;                   // chunk within image
        sidx[q] = (unsigned int)((2 * bb + rb) * (KB * 4096) + c * 256 + lane * 4);
        dofs[q] = (unsigned int)((wave * 8 + q) * 256 + lane * 4);   // A:0..8191, B:8192..
    }

    // ---- fragment LDS dword offsets (within ring slot; +cur*16384) ----
    // A frag i_abs (rows wr*128+16*i_abs): chunk g*2+kh, g = wr*8+i_abs.
    const int slotofs = ((lquad & 1) * 32 + lm) * 4;
    const int ao0 = (wr * 16 + lh2) * 256 + slotofs;          // i_abs adds 512
    const int bo0 = 8192 + (wc * 8 + lh2) * 256 + slotofs;    // j_abs adds 512

    f32x4 acc[32];
#pragma unroll
    for (int t = 0; t < 32; ++t) acc[t] = (f32x4){0.f, 0.f, 0.f, 0.f};

    // ---- prologue: stage tile 0 into slot 0, drain, publish ----
#pragma unroll
    for (int q = 0; q < 8; ++q)
        __builtin_amdgcn_global_load_lds(
            (const __attribute__((address_space(1))) void*)(sbase + sidx[q]),
            (__attribute__((address_space(3))) void*)(BUF + dofs[q]), 16, 0, 0);
    asm volatile("s_waitcnt vmcnt(0)" ::: "memory");
    __builtin_amdgcn_s_barrier();

    // ---- main loop: 4 phases per K-tile, one C-quadrant per phase ----
    int cur = 0;
    for (int kb = 0; kb < KB; ++kb, cur ^= 1) {
        const bool pf = (kb + 1 < KB);
        const unsigned int* bp = BUF + cur * 16384;
        unsigned int* np = BUF + (cur ^ 1) * 16384;
        const unsigned int soff = (unsigned int)((kb + 1) * 4096);
#pragma unroll
        for (int p = 0; p < 4; ++p) {
            const int Mh = p >> 1, Nh = p & 1;
            i32x8 a8[4], b8[2];
#pragma unroll
            for (int i = 0; i < 4; ++i) {
                const int off = ao0 + (Mh * 4 + i) * 512;
                i32x4 lo = *(const i32x4*)(bp + off);
                i32x4 hi = *(const i32x4*)(bp + off + 64);
                a8[i] = __builtin_shufflevector(lo, hi, 0, 1, 2, 3, 4, 5, 6, 7);
            }
#pragma unroll
            for (int j = 0; j < 2; ++j) {
                const int off = bo0 + (Nh * 2 + j) * 512;
                i32x4 lo = *(const i32x4*)(bp + off);
                i32x4 hi = *(const i32x4*)(bp + off + 64);
                b8[j] = __builtin_shufflevector(lo, hi, 0, 1, 2, 3, 4, 5, 6, 7);
            }
            if (pf) {
#pragma unroll
                for (int q = 0; q < 2; ++q)
                    __builtin_amdgcn_global_load_lds(
                        (const __attribute__((address_space(1))) void*)(sbase + sidx[p * 2 + q] + soff),
                        (__attribute__((address_space(3))) void*)(np + dofs[p * 2 + q]), 16, 0, 0);
            }
            __builtin_amdgcn_s_barrier();
            asm volatile("s_waitcnt lgkmcnt(0)" ::: "memory");
            __builtin_amdgcn_s_setprio(1);
#pragma unroll
            for (int i = 0; i < 4; ++i)
#pragma unroll
                for (int j = 0; j < 2; ++j)
                    acc[(Mh * 4 + i) * 4 + (Nh * 2 + j)] =
                        __builtin_amdgcn_mfma_scale_f32_16x16x128_f8f6f4(
                            a8[i], b8[j], acc[(Mh * 4 + i) * 4 + (Nh * 2 + j)],
                            0, 0, 0, SCALE_BYTE, 0, SCALE_BYTE);
            __builtin_amdgcn_s_setprio(0);
            if (p == 3 && pf)
                asm volatile("s_waitcnt vmcnt(0)" ::: "memory");  // tile kb+1 ready (aged >= 1 MFMA cluster)
            __builtin_amdgcn_s_barrier();
        }
    }

    // ---- epilogue. 16x16 C layout: col = lane&15, row = (lane>>4)*4+reg ----
    const int dp  = dper[0];
    const int gr0 = bx * 256 + wr * 128 + 4 * lquad;
    const int gc0 = by * 256 + wc * 64 + lm;
#pragma unroll
    for (int i = 0; i < 8; ++i)
#pragma unroll
        for (int r = 0; r < 4; ++r) {
            const int gr = gr0 + 16 * i + r;
            float e = 0.0f;
#pragma unroll
            for (int j = 0; j < 4; ++j) {
                float v = acc[i * 4 + j][r] * TEMP_INV;
                if (gr * dp == gc0 + 16 * j) pos[gr] = v;
                e += __expf(v);
            }
            e += __shfl_xor(e, 1);
            e += __shfl_xor(e, 2);
            e += __shfl_xor(e, 4);
            e += __shfl_xor(e, 8);
            if (lm == 0) atomicAdd(&rowsum[gr], e);
        }
}

// ---------------- final: loss = sum(log(rowsum) - pos)/B ----------------
__global__ void final_kernel(const float* __restrict__ rowsum,
                             const float* __restrict__ pos,
                             float* __restrict__ out, int B) {
    __shared__ float red[16];
    int tid = threadIdx.x;   // 1024 threads
    float s = 0.0f;
    for (int i = tid; i < B; i += blockDim.x)
        s += __logf(rowsum[i]) - pos[i];
    s += __shfl_xor(s, 32);
    s += __shfl_xor(s, 16);
    s += __shfl_xor(s, 8);
    s += __shfl_xor(s, 4);
    s += __shfl_xor(s, 2);
    s += __shfl_xor(s, 1);
    int w = tid >> 6, l = tid & 63;
    if (l == 0) red[w] = s;
    __syncthreads();
    if (tid == 0) {
        float t = 0.0f;
        int nw = blockDim.x >> 6;
        for (int i = 0; i < nw; ++i) t += red[i];
        out[0] = t / (float)B;
    }
}

extern "C" void kernel_launch(void* const* d_in, const int* in_sizes, int n_in,
                              void* d_out, int out_size, void* d_ws, size_t ws_size,
                              hipStream_t stream) {
    const float* Q   = (const float*)d_in[0];
    const float* Dm  = (const float*)d_in[1];
    const int* dper  = (const int*)d_in[2];
    float* out = (float*)d_out;

    const int DIM  = 1024;
    const int B    = in_sizes[0] / DIM;   // 4096
    const int Ntot = in_sizes[1] / DIM;   // 8192

    unsigned int* Q8 = (unsigned int*)d_ws;
    unsigned int* D8 = Q8 + (size_t)B * DIM / 4;
    float* rowsum = (float*)(D8 + (size_t)Ntot * DIM / 4);
    float* pos = rowsum + B;

    const int qSlots = B * DIM / 16;            // 262144
    const int dSlots = Ntot * DIM / 16;         // 524288
    cvt_kernel<<<(qSlots + dSlots) / 256, 256, 0, stream>>>(
        Q, Dm, Q8, D8, rowsum, qSlots, B, DIM);

    const int nblk = (B / 256) * (Ntot / 256);  // 512 = 8 * 64
    gemm_expsum_kernel<<<nblk, 512, 0, stream>>>(Q8, D8, dper, rowsum, pos, DIM);

    final_kernel<<<1, 1024, 0, stream>>>(rowsum, pos, out, B);
}

// Round 5
// 331.520 us; speedup vs baseline: 1.0252x; 1.0252x over previous
//
#include <hip/hip_runtime.h>

// InfoNCE loss:
//   loss = (1/B) * sum_i [ log(sum_j exp(Q_i . D_j / T)) - Q_i . D_{i*dp} / T ]
//
// R9 = R8's 4-phase 256x256 MX-fp8 schedule with the REGISTER-SPILL
// pathology fixed (R8: WRITE_SIZE 678MB of scratch, VGPR capped at 128 by
// __launch_bounds__(512,2), acc spilled, MfmaUtil 5%):
//   - __launch_bounds__(512) only: allocator free up to the natural
//     2-wave/SIMD budget (256 arch regs; acc can use the AGPR half of the
//     gfx950 unified file).
//   - 4 phases MANUALLY instantiated via macro with LITERAL phase index:
//     Mh/Nh constexpr, all acc[]/sidx[]/dofs[] indices are integer constant
//     expressions, frag temporaries are named vars (rule-#20 discipline --
//     no reliance on pragma unroll for regalloc correctness).
// Schedule per K-tile (BK=128), unchanged from R8:
//   phase p = C-quadrant (Mh,Nh):
//     12 ds_read_b128 (4 A + 2 B frags) from buf[cur]
//     2 global_load_lds chunks of tile kb+1 into buf[cur^1]
//     s_barrier ; lgkmcnt(0) ; setprio(1) ; 8 MFMA ; setprio(0)
//     [phase 3 only: vmcnt(0) -- prefetch aged >= 3 MFMA clusters]
//     s_barrier
// XCD swizzle (verified R7: FETCH halved): 512 blocks = 8 XCDs x (8x8).
//
// Tiled global layout (per matrix, unchanged): for 128-row block R, 128-wide
// k-block k0b: 16KB image = 16 chunks x 1KB. Chunk c = rg*2 + kh (rg=0..7
// 16-row group, kh=0..1 64-col half); slot l (16B) holds
//   X[R*128 + rg*16 + (l&15)][k0b*128 + kh*64 + (l>>4)*16 .. +16]   (fp8)
//
// ws layout (~12.1 MB):
//   [0)       Q8  B*K fp8     (4 MB)
//   [B*K)     D8  N*K fp8     (8 MB)
//   [+N*K)    rowsum B f32    (16 KB)  zeroed by cvt kernel
//   [+B*4)    pos    B f32    (16 KB)  written by gemm epilogue

#define TEMP_INV 50.0f
#define PRESCALE 16.0f
#define SCALE_BYTE 123   // e8m0: 2^(123-127) = 2^-4 per operand

typedef int   i32x4 __attribute__((ext_vector_type(4)));
typedef int   i32x8 __attribute__((ext_vector_type(8)));
typedef float f32x4 __attribute__((ext_vector_type(4)));

// ---------------- fp32 -> fp8 e4m3 (x16), pre-tiled; zero rowsum ----------
__global__ void cvt_kernel(const float* __restrict__ Q, const float* __restrict__ Dm,
                           unsigned int* __restrict__ Q8, unsigned int* __restrict__ D8,
                           float* __restrict__ rowsum, int qSlots, int B, int K) {
    const int gid = blockIdx.x * blockDim.x + threadIdx.x;
    if (gid < B) rowsum[gid] = 0.0f;
    const float* src;
    unsigned int* dst;
    int s;
    if (gid < qSlots) { src = Q;  dst = Q8; s = gid; }
    else              { src = Dm; dst = D8; s = gid - qSlots; }
    // Slot permutation within the 64-slot chunk (R7, kept): lane l handles
    // slot ((l&3)<<4)|(l>>2) -> reads coalesce to 256B runs.
    {
        const int l0 = s & 63;
        s = (s & ~63) | (((l0 & 3) << 4) | (l0 >> 2));
    }
    const int l   = s & 63;
    const int c   = (s >> 6) & 15;
    const int k0b = (s >> 10) & 7;
    const int R   = s >> 13;
    const int row = R * 128 + (c >> 1) * 16 + (l & 15);
    const int k   = k0b * 128 + (c & 1) * 64 + (l >> 4) * 16;
    const float* p = src + (size_t)row * K + k;
    unsigned int w[4];
#pragma unroll
    for (int d = 0; d < 4; ++d) {
        float4 v = *(const float4*)(p + d * 4);
        int t = __builtin_amdgcn_cvt_pk_fp8_f32(v.x * PRESCALE, v.y * PRESCALE, 0, false);
        t = __builtin_amdgcn_cvt_pk_fp8_f32(v.z * PRESCALE, v.w * PRESCALE, t, true);
        w[d] = (unsigned int)t;
    }
    *(uint4*)(dst + (size_t)s * 4) = make_uint4(w[0], w[1], w[2], w[3]);
}

// ---------------- fused MX-fp8 GEMM + row sum-exp + pos extraction --------
// grid: 1D 512 blocks (XCD-swizzled), 512 threads = 8 waves (2Mx4N),
// BK=128, 4-phase schedule, 128KB LDS ring.
__global__ __launch_bounds__(512) void gemm_expsum_kernel(
        const unsigned int* __restrict__ Q8, const unsigned int* __restrict__ D8,
        const int* __restrict__ dper,
        float* __restrict__ rowsum, float* __restrict__ pos, int K) {
    __shared__ unsigned int BUF[32768];   // 128KB: 2 x (A 8192 dw + B 8192 dw)

    const int tid   = threadIdx.x;
    const int wave  = tid >> 6;
    const int lane  = tid & 63;
    const int wr    = wave >> 2;         // 0..1 -> 128-row half
    const int wc    = wave & 3;          // 0..3 -> 64-col strip
    const int lquad = lane >> 4;
    const int lm    = lane & 15;
    const int lh2   = lquad >> 1;        // kh for fragment reads

    // XCD-aware bijective swizzle: 512 = 8 XCDs x (8bx x 8by) sub-tiles.
    const int f   = blockIdx.x;
    const int xcd = f & 7;
    const int sub = f >> 3;              // 0..63
    const int bx  = (xcd & 1) * 8 + (sub & 7);    // 0..15
    const int by  = (xcd >> 1) * 8 + (sub >> 3);  // 0..31

    const int KB = K >> 7;               // 8 K-tiles of 128

    // ---- staging: wave w owns chunks flat = w*8 + 2p + q (p=phase) ----
    // waves 0-3 stage A (chunks 0..31), waves 4-7 stage B (chunks 32..63).
    const unsigned int* sbase = (wave < 4) ? Q8 : D8;
    const int bb = (wave < 4) ? bx : by;
    unsigned int sidx[8];                // dword index from sbase (+kb*4096)
    unsigned int dofs[8];                // dword offset within ring slot
#pragma unroll
    for (int q = 0; q < 8; ++q) {
        const int fl = (wave & 3) * 8 + q;        // 0..31 within A or B set
        const int rb = fl >> 4;                   // which 128-row image
        const int c  = fl & 15;                   // chunk within image
        sidx[q] = (unsigned int)((2 * bb + rb) * (KB * 4096) + c * 256 + lane * 4);
        dofs[q] = (unsigned int)((wave * 8 + q) * 256 + lane * 4);   // A:0..8191, B:8192..
    }

    // ---- fragment LDS dword offsets (within ring slot; bp adds cur) ----
    const int slotofs = ((lquad & 1) * 32 + lm) * 4;
    const int ao0 = (wr * 16 + lh2) * 256 + slotofs;          // A frag i_abs: +i_abs*512
    const int bo0 = 8192 + (wc * 8 + lh2) * 256 + slotofs;    // B frag j_abs: +j_abs*512

    f32x4 acc[32];
#pragma unroll
    for (int t = 0; t < 32; ++t) acc[t] = (f32x4){0.f, 0.f, 0.f, 0.f};

    // ---- prologue: stage tile 0 into slot 0, drain, publish ----
#pragma unroll
    for (int q = 0; q < 8; ++q)
        __builtin_amdgcn_global_load_lds(
            (const __attribute__((address_space(1))) void*)(sbase + sidx[q]),
            (__attribute__((address_space(3))) void*)(BUF + dofs[q]), 16, 0, 0);
    asm volatile("s_waitcnt vmcnt(0)" ::: "memory");
    __builtin_amdgcn_s_barrier();

    // One phase, LITERAL index PP (0..3). All register-file indices are
    // integer constant expressions -> nothing can fall to scratch.
#define LDFRAG(dst_, base_, off_) do {                                       \
        i32x4 lo_ = *(const i32x4*)((base_) + (off_));                       \
        i32x4 hi_ = *(const i32x4*)((base_) + (off_) + 64);                  \
        dst_ = __builtin_shufflevector(lo_, hi_, 0, 1, 2, 3, 4, 5, 6, 7);    \
    } while (0)

#define MFMA1(AA, BB, IDX)                                                   \
        acc[IDX] = __builtin_amdgcn_mfma_scale_f32_16x16x128_f8f6f4(         \
            AA, BB, acc[IDX], 0, 0, 0, SCALE_BYTE, 0, SCALE_BYTE)

#define PHASE(PP, pf_) do {                                                  \
        constexpr int Mh_ = (PP) >> 1, Nh_ = (PP) & 1;                       \
        i32x8 A0, A1, A2, A3, B0, B1;                                        \
        LDFRAG(A0, bp, ao0 + (Mh_ * 4 + 0) * 512);                           \
        LDFRAG(A1, bp, ao0 + (Mh_ * 4 + 1) * 512);                           \
        LDFRAG(A2, bp, ao0 + (Mh_ * 4 + 2) * 512);                           \
        LDFRAG(A3, bp, ao0 + (Mh_ * 4 + 3) * 512);                           \
        LDFRAG(B0, bp, bo0 + (Nh_ * 2 + 0) * 512);                           \
        LDFRAG(B1, bp, bo0 + (Nh_ * 2 + 1) * 512);                           \
        if (pf_) {                                                           \
            __builtin_amdgcn_global_load_lds(                                \
                (const __attribute__((address_space(1))) void*)(sbase + sidx[(PP) * 2] + soff), \
                (__attribute__((address_space(3))) void*)(np + dofs[(PP) * 2]), 16, 0, 0); \
            __builtin_amdgcn_global_load_lds(                                \
                (const __attribute__((address_space(1))) void*)(sbase + sidx[(PP) * 2 + 1] + soff), \
                (__attribute__((address_space(3))) void*)(np + dofs[(PP) * 2 + 1]), 16, 0, 0); \
        }                                                                    \
        __builtin_amdgcn_s_barrier();                                        \
        asm volatile("s_waitcnt lgkmcnt(0)" ::: "memory");                   \
        __builtin_amdgcn_s_setprio(1);                                       \
        MFMA1(A0, B0, (Mh_ * 4 + 0) * 4 + Nh_ * 2 + 0);                      \
        MFMA1(A0, B1, (Mh_ * 4 + 0) * 4 + Nh_ * 2 + 1);                      \
        MFMA1(A1, B0, (Mh_ * 4 + 1) * 4 + Nh_ * 2 + 0);                      \
        MFMA1(A1, B1, (Mh_ * 4 + 1) * 4 + Nh_ * 2 + 1);                      \
        MFMA1(A2, B0, (Mh_ * 4 + 2) * 4 + Nh_ * 2 + 0);                      \
        MFMA1(A2, B1, (Mh_ * 4 + 2) * 4 + Nh_ * 2 + 1);                      \
        MFMA1(A3, B0, (Mh_ * 4 + 3) * 4 + Nh_ * 2 + 0);                      \
        MFMA1(A3, B1, (Mh_ * 4 + 3) * 4 + Nh_ * 2 + 1);                      \
        __builtin_amdgcn_s_setprio(0);                                       \
        if ((PP) == 3 && (pf_))                                              \
            asm volatile("s_waitcnt vmcnt(0)" ::: "memory");                 \
        __builtin_amdgcn_s_barrier();                                        \
    } while (0)

    int cur = 0;
    for (int kb = 0; kb < KB; ++kb, cur ^= 1) {
        const bool pf = (kb + 1 < KB);
        const unsigned int* bp = BUF + cur * 16384;
        unsigned int* np = BUF + (cur ^ 1) * 16384;
        const unsigned int soff = (unsigned int)((kb + 1) * 4096);
        PHASE(0, pf);
        PHASE(1, pf);
        PHASE(2, pf);
        PHASE(3, pf);
    }
#undef PHASE
#undef MFMA1
#undef LDFRAG

    // ---- epilogue. 16x16 C layout: col = lane&15, row = (lane>>4)*4+reg ----
    const int dp  = dper[0];
    const int gr0 = bx * 256 + wr * 128 + 4 * lquad;
    const int gc0 = by * 256 + wc * 64 + lm;
#pragma unroll
    for (int i = 0; i < 8; ++i)
#pragma unroll
        for (int r = 0; r < 4; ++r) {
            const int gr = gr0 + 16 * i + r;
            float e = 0.0f;
#pragma unroll
            for (int j = 0; j < 4; ++j) {
                float v = acc[i * 4 + j][r] * TEMP_INV;
                if (gr * dp == gc0 + 16 * j) pos[gr] = v;
                e += __expf(v);
            }
            e += __shfl_xor(e, 1);
            e += __shfl_xor(e, 2);
            e += __shfl_xor(e, 4);
            e += __shfl_xor(e, 8);
            if (lm == 0) atomicAdd(&rowsum[gr], e);
        }
}

// ---------------- final: loss = sum(log(rowsum) - pos)/B ----------------
__global__ void final_kernel(const float* __restrict__ rowsum,
                             const float* __restrict__ pos,
                             float* __restrict__ out, int B) {
    __shared__ float red[16];
    int tid = threadIdx.x;   // 1024 threads
    float s = 0.0f;
    for (int i = tid; i < B; i += blockDim.x)
        s += __logf(rowsum[i]) - pos[i];
    s += __shfl_xor(s, 32);
    s += __shfl_xor(s, 16);
    s += __shfl_xor(s, 8);
    s += __shfl_xor(s, 4);
    s += __shfl_xor(s, 2);
    s += __shfl_xor(s, 1);
    int w = tid >> 6, l = tid & 63;
    if (l == 0) red[w] = s;
    __syncthreads();
    if (tid == 0) {
        float t = 0.0f;
        int nw = blockDim.x >> 6;
        for (int i = 0; i < nw; ++i) t += red[i];
        out[0] = t / (float)B;
    }
}

extern "C" void kernel_launch(void* const* d_in, const int* in_sizes, int n_in,
                              void* d_out, int out_size, void* d_ws, size_t ws_size,
                              hipStream_t stream) {
    const float* Q   = (const float*)d_in[0];
    const float* Dm  = (const float*)d_in[1];
    const int* dper  = (const int*)d_in[2];
    float* out = (float*)d_out;

    const int DIM  = 1024;
    const int B    = in_sizes[0] / DIM;   // 4096
    const int Ntot = in_sizes[1] / DIM;   // 8192

    unsigned int* Q8 = (unsigned int*)d_ws;
    unsigned int* D8 = Q8 + (size_t)B * DIM / 4;
    float* rowsum = (float*)(D8 + (size_t)Ntot * DIM / 4);
    float* pos = rowsum + B;

    const int qSlots = B * DIM / 16;            // 262144
    const int dSlots = Ntot * DIM / 16;         // 524288
    cvt_kernel<<<(qSlots + dSlots) / 256, 256, 0, stream>>>(
        Q, Dm, Q8, D8, rowsum, qSlots, B, DIM);

    const int nblk = (B / 256) * (Ntot / 256);  // 512 = 8 * 64
    gemm_expsum_kernel<<<nblk, 512, 0, stream>>>(Q8, D8, dper, rowsum, pos, DIM);

    final_kernel<<<1, 1024, 0, stream>>>(rowsum, pos, out, B);
}